// Round 7
// baseline (375.631 us; speedup 1.0000x reference)
//
#include <hip/hip_runtime.h>
#include <math.h>

#define S       512
#define BATCH   32
#define NDIAG   (2 * S - 1)      // 1023
#define LDSP    68
#define INV_LN2 1.4426950408889634f
#define CLAMPM  1.0e38f          // NaN guard: ms = min(dd,up,lf,CLAMPM) is finite
#define INFF    __builtin_huge_valf()

__device__ __forceinline__ float ex2(float x) { return __builtin_amdgcn_exp2f(x); }
__device__ __forceinline__ float lg2(float x) { return __builtin_amdgcn_logf(x); }

// lane i <- src[i-1]; lane 0 <- old. (DPP wave_shr:1, verified round 3.)
__device__ __forceinline__ float dpp_shr1(float src, float old) {
    return __int_as_float(__builtin_amdgcn_update_dpp(
        __float_as_int(old), __float_as_int(src), 0x138, 0xf, 0xf, false));
}

// ---------------------------------------------------------------------------
// Kernel 0: fill invalid [p][i] slots (j = p-i out of range) with +inf.
// ---------------------------------------------------------------------------
__global__ __launch_bounds__(256) void fill_invalid(float* __restrict__ Dd) {
    const int b = blockIdx.y;
    const int p = blockIdx.x * 4 + (threadIdx.x >> 6);
    const int l = threadIdx.x & 63;
    if (p >= NDIAG) return;
    float* base = Dd + ((size_t)b * NDIAG + p) * S;
    for (int i = l; i < S; i += 64)
        if ((unsigned)(p - i) >= (unsigned)S) base[i] = INFF;
}

// ---------------------------------------------------------------------------
// Kernel 1: D2[b][p][i] = (|x_i|^2+|y_j|^2-2<x_i,y_j>)/ln2, p=i+j anti-diag
// layout (i-contiguous). LDS-staged epilogue -> coalesced diagonal writes.
// ---------------------------------------------------------------------------
__global__ __launch_bounds__(256) void pairdist_kernel(
    const float* __restrict__ X, const float* __restrict__ Y,
    float* __restrict__ Dd)
{
    const int b   = blockIdx.z;
    const int i0  = blockIdx.y * 64;
    const int j0  = blockIdx.x * 64;
    const int tid = threadIdx.x;

    __shared__ float XsT[64][LDSP];
    __shared__ float YsT[64][LDSP];
    __shared__ float x2s[64], y2s[64];
    __shared__ float Ct[64][66];   // [iL][jL]; stride 66 -> diag reads conflict-free

    const float* Xb = X + ((size_t)b * S + i0) * 64;
    const float* Yb = Y + ((size_t)b * S + j0) * 64;

#pragma unroll
    for (int c = 0; c < 4; ++c) {
        int idx = c * 1024 + tid * 4;
        int row = idx >> 6;
        int k   = idx & 63;
        float4 vx = *(const float4*)(Xb + (size_t)row * 64 + k);
        float4 vy = *(const float4*)(Yb + (size_t)row * 64 + k);
        XsT[k + 0][row] = vx.x; XsT[k + 1][row] = vx.y;
        XsT[k + 2][row] = vx.z; XsT[k + 3][row] = vx.w;
        YsT[k + 0][row] = vy.x; YsT[k + 1][row] = vy.y;
        YsT[k + 2][row] = vy.z; YsT[k + 3][row] = vy.w;
    }
    __syncthreads();

    if (tid < 64) {
        float s = 0.f;
#pragma unroll 8
        for (int k = 0; k < 64; ++k) { float v = XsT[k][tid]; s = fmaf(v, v, s); }
        x2s[tid] = s;
    } else if (tid < 128) {
        int r = tid - 64;
        float s = 0.f;
#pragma unroll 8
        for (int k = 0; k < 64; ++k) { float v = YsT[k][r]; s = fmaf(v, v, s); }
        y2s[r] = s;
    }
    __syncthreads();

    const int tx = tid & 15;
    const int ty = tid >> 4;
    float acc[4][4] = {};
#pragma unroll 4
    for (int k = 0; k < 64; ++k) {
        float4 a  = *(const float4*)&XsT[k][ty * 4];
        float4 bb = *(const float4*)&YsT[k][tx * 4];
        float av[4] = {a.x, a.y, a.z, a.w};
        float bv[4] = {bb.x, bb.y, bb.z, bb.w};
#pragma unroll
        for (int r = 0; r < 4; ++r)
#pragma unroll
            for (int c = 0; c < 4; ++c)
                acc[r][c] = fmaf(av[r], bv[c], acc[r][c]);
    }

#pragma unroll
    for (int r = 0; r < 4; ++r) {
        float xr = x2s[ty * 4 + r];
#pragma unroll
        for (int c = 0; c < 4; ++c)
            Ct[ty * 4 + r][tx * 4 + c] = (xr + y2s[tx * 4 + c] - 2.0f * acc[r][c]) * INV_LN2;
    }
    __syncthreads();

    const int g4 = tid >> 6, l64 = tid & 63;
    float* Dbase = Dd + (size_t)b * NDIAG * S + (size_t)(i0 + j0) * S + i0;
    for (int pl = g4; pl < 127; pl += 4) {
        int lo = pl > 63 ? pl - 63 : 0;
        int hi = pl < 63 ? pl : 63;
        int iL = lo + l64;
        if (iL <= hi) Dbase[(size_t)pl * S + iL] = Ct[iL][pl - iL];
    }
}

// ---------------------------------------------------------------------------
// Kernel 2: log2-domain soft-DTW DP. One wave per batch; lane l owns rows
// 8l..8l+7; step p computes the lane's 8 cells of anti-diagonal p:
//   ms = min(dd, up, lf, 1e38)                       (finite -> no inf-inf)
//   e  = exp2(ms-dd) + exp2(ms-up) + exp2(ms-lf)     (exp2(-inf) = 0)
//   CV = D2 + ms - log2(e)                           (e==0 -> CV = +inf)
// All 8 cells per step are independent (inputs from diagonals p-1/p-2), so
// the serial chain is one cell deep; issue-bound, not latency-bound.
// No barriers, no LDS, no rescaling controller; math == reference softmin
// in log2 units (values in [0, ~9.4e4] or +inf, NaN-free by induction).
// ---------------------------------------------------------------------------
__global__ __launch_bounds__(64) void softdtw_dp_log(
    const float* __restrict__ Dd, float* __restrict__ out)
{
    const int b    = blockIdx.x;
    const int lane = threadIdx.x;
    const float* __restrict__ DbU = Dd + (size_t)b * NDIAG * S;
    const int loff = lane << 3;

    float Av[8], Bv[8];
#pragma unroll
    for (int k = 0; k < 8; ++k) { Av[k] = INFF; Bv[k] = INFF; }

    float4 qa[8], qb[8];
#pragma unroll
    for (int u = 0; u < 8; ++u) {
        const float* rp = DbU + ((size_t)u << 9) + loff;
        qa[u] = *(const float4*)rp;
        qb[u] = *(const float4*)(rp + 4);
    }

#define CELL(DD, UP, LF, Q, DST)                                               \
    {                                                                          \
        float _ms = fminf(fminf((DD), (UP)), fminf((LF), CLAMPM));             \
        float _e  = ex2(_ms - (DD)) + ex2(_ms - (UP)) + ex2(_ms - (LF));       \
        DST = (Q) + (_ms - lg2(_e));                                           \
    }

#define DP_STEP(SLOT, PV, CV, CORNER, ROWN)                                    \
    {                                                                          \
        float4 _ea = qa[SLOT], _eb = qb[SLOT];                                 \
        { const float* _rp = DbU + ((size_t)(ROWN) << 9) + loff;               \
          qa[SLOT] = *(const float4*)_rp;                                      \
          qb[SLOT] = *(const float4*)(_rp + 4); }                              \
        float a_sh = dpp_shr1(PV[7], INFF);                                    \
        float b_sh = dpp_shr1(CV[7], (CORNER));                                \
        CELL(CV[6], PV[6], PV[7], _eb.w, CV[7])                                \
        CELL(CV[5], PV[5], PV[6], _eb.z, CV[6])                                \
        CELL(CV[4], PV[4], PV[5], _eb.y, CV[5])                                \
        CELL(CV[3], PV[3], PV[4], _eb.x, CV[4])                                \
        CELL(CV[2], PV[2], PV[3], _ea.w, CV[3])                                \
        CELL(CV[1], PV[1], PV[2], _ea.z, CV[2])                                \
        CELL(CV[0], PV[0], PV[1], _ea.y, CV[1])                                \
        CELL(b_sh,  a_sh,  PV[0], _ea.x, CV[0])                                \
    }

    // ---- peeled p = 0..7 (corner R[-1,-1]=0 injected only at p=0) ----
    DP_STEP(0, Av, Bv, 0.0f,  8)
    DP_STEP(1, Bv, Av, INFF,  9)
    DP_STEP(2, Av, Bv, INFF, 10)
    DP_STEP(3, Bv, Av, INFF, 11)
    DP_STEP(4, Av, Bv, INFF, 12)
    DP_STEP(5, Bv, Av, INFF, 13)
    DP_STEP(6, Av, Bv, INFF, 14)
    DP_STEP(7, Bv, Av, INFF, 15)

    // ---- main loop p = 8..1015, groups of 8 (slot = p & 7) ----
#pragma unroll 1
    for (int p8 = 8; p8 <= 1008; p8 += 8) {
        const int r = p8 + 8;
        DP_STEP(0, Av, Bv, INFF, (r + 0 > 1022 ? 1022 : r + 0))
        DP_STEP(1, Bv, Av, INFF, (r + 1 > 1022 ? 1022 : r + 1))
        DP_STEP(2, Av, Bv, INFF, (r + 2 > 1022 ? 1022 : r + 2))
        DP_STEP(3, Bv, Av, INFF, (r + 3 > 1022 ? 1022 : r + 3))
        DP_STEP(4, Av, Bv, INFF, (r + 4 > 1022 ? 1022 : r + 4))
        DP_STEP(5, Bv, Av, INFF, (r + 5 > 1022 ? 1022 : r + 5))
        DP_STEP(6, Av, Bv, INFF, (r + 6 > 1022 ? 1022 : r + 6))
        DP_STEP(7, Bv, Av, INFF, (r + 7 > 1022 ? 1022 : r + 7))
    }

    // ---- tail p = 1016..1022 (prefetch clamped to last row, unused) ----
    DP_STEP(0, Av, Bv, INFF, 1022)
    DP_STEP(1, Bv, Av, INFF, 1022)
    DP_STEP(2, Av, Bv, INFF, 1022)
    DP_STEP(3, Bv, Av, INFF, 1022)
    DP_STEP(4, Av, Bv, INFF, 1022)
    DP_STEP(5, Bv, Av, INFF, 1022)
    DP_STEP(6, Av, Bv, INFF, 1022)
#undef DP_STEP
#undef CELL

    // p=1022 is even -> its values sit in Bv; R[511,511] = lane 63, k=7.
    if (lane == 63)
        out[b] = 0.69314718055994531f * Bv[7];
}

// ---------------------------------------------------------------------------
extern "C" void kernel_launch(void* const* d_in, const int* in_sizes, int n_in,
                              void* d_out, int out_size, void* d_ws, size_t ws_size,
                              hipStream_t stream)
{
    const float* X = (const float*)d_in[0];
    const float* Y = (const float*)d_in[1];
    float* out = (float*)d_out;
    float* Dd  = (float*)d_ws;   // 32*1023*512*4 B ~= 64 MiB

    fill_invalid<<<dim3(256, BATCH), 256, 0, stream>>>(Dd);

    dim3 g1(S / 64, S / 64, BATCH);
    pairdist_kernel<<<g1, 256, 0, stream>>>(X, Y, Dd);

    softdtw_dp_log<<<BATCH, 64, 0, stream>>>(Dd, out);
}